// Round 1
// baseline (356.052 us; speedup 1.0000x reference)
//
#include <hip/hip_runtime.h>
#include <math.h>

#define WH 16384
#define C64 64

// Device-scope HW fp32 atomic (global_atomic_add_f32), avoids CAS loop.
__device__ __forceinline__ void atomAddF(float* p, float v) {
    __hip_atomic_fetch_add(p, v, __ATOMIC_RELAXED, __HIP_MEMORY_SCOPE_AGENT);
}

// ---------------- zero workspace (G + s regions; ws is poisoned 0xAA) --------
__global__ void zero_ws_kernel(float* __restrict__ p, int n) {
    int i = blockIdx.x * 256 + threadIdx.x;
    if (i < n) p[i] = 0.f;
}

// ---------------- pass A: per-(n,input) channel gram G = X X^T and sums s ----
// grid (16 chunks, 16 n, 2 inp), block 256. Each block: 1024 px = 4 tiles of 256.
// LDS tile [64 ch][256 px], XOR-swizzled quads: physical quad = q ^ (row & 7)
// -> all ds_read_b128 in the compute loop are bank-conflict-free.
__global__ __launch_bounds__(256, 2) void gram_kernel(
    const float* __restrict__ xR, const float* __restrict__ xT,
    float* __restrict__ G, float* __restrict__ sv) {
    __shared__ float lds[16384];  // 64 KB: tile, later reused as 4x4096 reduce scratch
    const int t = threadIdx.x;
    const int wave = t >> 6;
    const int lane = t & 63;
    const int ti = lane & 7;   // row group: rows ti + 8i (strided)
    const int tj = lane >> 3;  // col group: cols tj + 8j
    const int n = blockIdx.y;
    const int inp = blockIdx.z;
    const float* __restrict__ X = (inp ? xT : xR) + (size_t)n * C64 * WH;
    float* __restrict__ Gout = G + (size_t)(inp * 16 + n) * 4096;
    float* __restrict__ Sout = sv + (size_t)(inp * 16 + n) * 64;

    float acc[8][8];
#pragma unroll
    for (int i = 0; i < 8; ++i)
#pragma unroll
        for (int j = 0; j < 8; ++j) acc[i][j] = 0.f;
    float srow[8];
#pragma unroll
    for (int i = 0; i < 8; ++i) srow[i] = 0.f;

    const int p_base = blockIdx.x << 10;
    for (int tile = 0; tile < 4; ++tile) {
        const int p0 = p_base + (tile << 8);
        __syncthreads();  // previous tile's readers done
        // stage: per iteration each wave loads one full 1 KB row (perfect coalescing)
#pragma unroll
        for (int it = 0; it < 16; ++it) {
            const int row = (it << 2) + wave;
            float4 v = *(const float4*)(X + (size_t)row * WH + p0 + (lane << 2));
            *(float4*)&lds[(row << 8) + ((lane ^ (row & 7)) << 2)] = v;
        }
        __syncthreads();
        // compute: wave w handles pixel-quads 16w..16w+15
#pragma unroll 2
        for (int qq = 0; qq < 16; ++qq) {
            const int q = (wave << 4) + qq;
            const int oa = (q ^ ti) << 2;
            const int ob = (q ^ tj) << 2;
            float4 a[8], b[8];
#pragma unroll
            for (int i = 0; i < 8; ++i) a[i] = *(const float4*)&lds[((ti + 8 * i) << 8) + oa];
#pragma unroll
            for (int j = 0; j < 8; ++j) b[j] = *(const float4*)&lds[((tj + 8 * j) << 8) + ob];
#pragma unroll
            for (int i = 0; i < 8; ++i)
#pragma unroll
                for (int j = 0; j < 8; ++j)
                    acc[i][j] += a[i].x * b[j].x + a[i].y * b[j].y +
                                 a[i].z * b[j].z + a[i].w * b[j].w;
            if (tj == 0) {
#pragma unroll
                for (int i = 0; i < 8; ++i)
                    srow[i] += a[i].x + a[i].y + a[i].z + a[i].w;
            }
        }
    }
    __syncthreads();
    // cross-wave reduce of the 64x64 partials through LDS, then one atomic per entry
    {
        float* sc = lds + (wave << 12);
#pragma unroll
        for (int i = 0; i < 8; ++i)
#pragma unroll
            for (int j = 0; j < 8; ++j)
                sc[((ti + 8 * i) << 6) + (tj + 8 * j)] = acc[i][j];
    }
    __syncthreads();
#pragma unroll
    for (int m = 0; m < 16; ++m) {
        const int e = t + (m << 8);
        float v = lds[e] + lds[4096 + e] + lds[8192 + e] + lds[12288 + e];
        atomAddF(&Gout[e], v);
    }
    if (tj == 0) {
#pragma unroll
        for (int i = 0; i < 8; ++i) atomAddF(&Sout[ti + 8 * i], srow[i]);
    }
}

// ---------------- logits: rs = W G W^T + (Ws)b^T + b(Ws)^T + WH*b b^T --------
// grid (16 n, 2 inp), block 256. Writes raw logits into att[n][inp*64+d][e].
__global__ __launch_bounds__(256) void logits_kernel(
    const float* __restrict__ WR, const float* __restrict__ bR,
    const float* __restrict__ WT, const float* __restrict__ bT,
    const float* __restrict__ G, const float* __restrict__ sv,
    float* __restrict__ att) {
    __shared__ float ldsW[4096];
    __shared__ float ldsWt[4096];
    __shared__ float ldsG[4096];  // G, then reused for M1 = W*G
    __shared__ float ldsS[64];
    __shared__ float ldsU[64];
    const int t = threadIdx.x;
    const int n = blockIdx.x;
    const int inp = blockIdx.y;
    const float* __restrict__ W = inp ? WT : WR;
    const float* __restrict__ b = inp ? bT : bR;
    const float* __restrict__ Gn = G + (size_t)(inp * 16 + n) * 4096;
    const float* __restrict__ sn = sv + (size_t)(inp * 16 + n) * 64;
#pragma unroll
    for (int m = 0; m < 16; ++m) {
        const int idx = t + (m << 8);
        const float w = W[idx];
        ldsW[idx] = w;
        ldsWt[((idx & 63) << 6) + (idx >> 6)] = w;  // Wt[c][e] = W[e][c]
        ldsG[idx] = Gn[idx];
    }
    if (t < 64) ldsS[t] = sn[t];
    __syncthreads();
    if (t < 64) {
        float u = 0.f;
        for (int c = 0; c < 64; ++c) u += ldsW[(t << 6) + c] * ldsS[c];
        ldsU[t] = u;  // u = W s
    }
    const int d = t >> 2;
    const int e0 = (t & 3) << 4;
    float a[16];
#pragma unroll
    for (int e = 0; e < 16; ++e) a[e] = 0.f;
    for (int c = 0; c < 64; ++c) {
        const float w = ldsW[(d << 6) + c];
#pragma unroll
        for (int e = 0; e < 16; ++e) a[e] += w * ldsG[(c << 6) + e0 + e];
    }
    __syncthreads();  // all reads of G done
#pragma unroll
    for (int e = 0; e < 16; ++e) ldsG[(d << 6) + e0 + e] = a[e];  // M1 = W*G
    __syncthreads();
    float r[16];
#pragma unroll
    for (int e = 0; e < 16; ++e) r[e] = 0.f;
    for (int c = 0; c < 64; ++c) {
        const float m1 = ldsG[(d << 6) + c];
#pragma unroll
        for (int e = 0; e < 16; ++e) r[e] += m1 * ldsWt[(c << 6) + e0 + e];
    }
    const float ud = ldsU[d];
    const float bd = b[d];
    float* __restrict__ L = att + ((size_t)n * 128 + inp * 64 + d) * 64;
#pragma unroll
    for (int e = 0; e < 16; ++e) {
        const int ee = e0 + e;
        L[ee] = r[e] + ud * b[ee] + bd * ldsU[ee] + 16384.f * bd * b[ee];
    }
}

// ---------------- softmax over the 128 rows, per (n, column) -----------------
// grid 16, block 64: thread t owns column t of att[n] (logits ~2600 -> max-sub).
__global__ __launch_bounds__(64) void softmax_kernel(float* __restrict__ att) {
    const int n = blockIdx.x;
    const int t = threadIdx.x;
    float* __restrict__ A = att + (size_t)n * 8192;
    float v[128];
#pragma unroll 8
    for (int k = 0; k < 128; ++k) v[k] = A[(k << 6) + t];
    float mx = -1e30f;
#pragma unroll 8
    for (int k = 0; k < 128; ++k) mx = fmaxf(mx, v[k]);
    float sum = 0.f;
#pragma unroll 8
    for (int k = 0; k < 128; ++k) {
        v[k] = __expf(v[k] - mx);
        sum += v[k];
    }
    const float inv = 1.f / sum;
#pragma unroll 8
    for (int k = 0; k < 128; ++k) A[(k << 6) + t] = v[k] * inv;
}

// ---------------- pass B: out[n,c,p] = sum_k att[n,k,c] * [xR;xT][n,k,p] -----
// grid (128 px-chunks, 16 n), block 256. LDS holds [2][64][128] input tile
// (64 KB); att rows read through L1 (32 KB, fully L1/L2 resident, broadcast).
__global__ __launch_bounds__(256, 2) void out_kernel(
    const float* __restrict__ xR, const float* __restrict__ xT,
    const float* __restrict__ att, float* __restrict__ out) {
    __shared__ float lx[16384];
    const int t = threadIdx.x;
    const int n = blockIdx.y;
    const int p0 = blockIdx.x << 7;
    const float* __restrict__ XR = xR + (size_t)n * C64 * WH;
    const float* __restrict__ XT = xT + (size_t)n * C64 * WH;
    const float* __restrict__ attn = att + (size_t)n * 8192;

#pragma unroll
    for (int it = 0; it < 16; ++it) {
        const int f = (it << 10) + (t << 2);
        const int inp = f >> 13;
        const int k = (f >> 7) & 63;
        const int px = f & 127;
        const float* __restrict__ X = inp ? XT : XR;
        float4 v = *(const float4*)(X + (size_t)k * WH + p0 + px);
        *(float4*)&lx[f] = v;
    }
    __syncthreads();

    const int ci = t >> 5;  // c rows 8ci..8ci+7
    const int pj = t & 31;  // pixel quad
    float4 acc[8];
#pragma unroll
    for (int i = 0; i < 8; ++i) acc[i] = make_float4(0.f, 0.f, 0.f, 0.f);

#pragma unroll
    for (int half = 0; half < 2; ++half) {
        const float* __restrict__ lxh = lx + (half << 13);
        const float* __restrict__ ah = attn + (half << 12) + (ci << 3);
#pragma unroll 4
        for (int k = 0; k < 64; ++k) {
            const float4 xv = *(const float4*)&lxh[(k << 7) + (pj << 2)];
            const float4 a0 = *(const float4*)(ah + (k << 6));
            const float4 a1 = *(const float4*)(ah + (k << 6) + 4);
            const float av[8] = {a0.x, a0.y, a0.z, a0.w, a1.x, a1.y, a1.z, a1.w};
#pragma unroll
            for (int i = 0; i < 8; ++i) {
                acc[i].x += av[i] * xv.x;
                acc[i].y += av[i] * xv.y;
                acc[i].z += av[i] * xv.z;
                acc[i].w += av[i] * xv.w;
            }
        }
    }
    float* __restrict__ outn = out + (size_t)n * C64 * WH + p0 + (pj << 2);
#pragma unroll
    for (int i = 0; i < 8; ++i)
        *(float4*)(outn + (size_t)((ci << 3) + i) * WH) = acc[i];
}

extern "C" void kernel_launch(void* const* d_in, const int* in_sizes, int n_in,
                              void* d_out, int out_size, void* d_ws, size_t ws_size,
                              hipStream_t stream) {
    const float* xR = (const float*)d_in[0];
    const float* xT = (const float*)d_in[1];
    const float* WR = (const float*)d_in[2];
    const float* bR = (const float*)d_in[3];
    const float* WT = (const float*)d_in[4];
    const float* bT = (const float*)d_in[5];
    float* out = (float*)d_out;

    // ws layout (floats): G [2][16][4096] | s [2][16][64] | att/logits [16][128][64]
    float* ws = (float*)d_ws;
    float* G = ws;                  // 131072 floats
    float* sv = ws + 131072;        // 2048 floats
    float* att = ws + 133120;       // 131072 floats  (~1.01 MB total)

    zero_ws_kernel<<<520, 256, 0, stream>>>(ws, 133120);
    gram_kernel<<<dim3(16, 16, 2), 256, 0, stream>>>(xR, xT, G, sv);
    logits_kernel<<<dim3(16, 2), 256, 0, stream>>>(WR, bR, WT, bT, G, sv, att);
    softmax_kernel<<<16, 64, 0, stream>>>(att);
    out_kernel<<<dim3(128, 16), 256, 0, stream>>>(xR, xT, att, out);
}